// Round 8
// baseline (176.364 us; speedup 1.0000x reference)
//
#include <hip/hip_runtime.h>
#include <stdint.h>

#define B_SZ  4096
#define HEADS 16
#define HD    64
#define M_SZ  4096
#define K_IN  1024
#define SW    72    // padded LDS row stride (f16 elems)
#define LOG2E 1.44269504088896f

typedef _Float16 f16;
typedef f16  f16x2 __attribute__((ext_vector_type(2)));
typedef f16  f16x4 __attribute__((ext_vector_type(4)));
typedef f16  f16x8 __attribute__((ext_vector_type(8)));
typedef float f32x4 __attribute__((ext_vector_type(4)));

union U8 { uint4 u4; f16x8 h8; unsigned int ui[4]; unsigned short us[8]; };

__device__ __forceinline__ unsigned short f2h(float f) {
    _Float16 h = (_Float16)f;
    return __builtin_bit_cast(unsigned short, h);
}
__device__ __forceinline__ f16x8 ldsv8(const unsigned short* p) {
    U8 u; u.u4 = *reinterpret_cast<const uint4*>(p); return u.h8;
}

#if __has_builtin(__builtin_amdgcn_exp2f)
#define EXP2F(x) __builtin_amdgcn_exp2f(x)
#else
#define EXP2F(x) __expf((x) * 0.6931471805599453f)
#endif

// async global -> LDS: lane i's 16 B land at ldsbase + i*16
__device__ __forceinline__ void gload_lds16(const void* g, void* l) {
    __builtin_amdgcn_global_load_lds(
        (const __attribute__((address_space(1))) void*)g,
        (__attribute__((address_space(3))) void*)l, 16, 0, 0);
}

// ---------------------------------------------------------------------------
// Kernel 0: f32 -> f16 conversion of x and Wq (one pass).  [round-0 verbatim]
// ---------------------------------------------------------------------------
__global__ __launch_bounds__(256) void k_conv(const float* __restrict__ x,
                                              const float* __restrict__ Wq,
                                              unsigned short* __restrict__ xh,
                                              unsigned short* __restrict__ Wh) {
    const int b = blockIdx.x;
    const float* src;
    unsigned short* dst;
    size_t base;
    if (b < 2048) { src = x;  dst = xh; base = (size_t)b * 2048; }
    else          { src = Wq; dst = Wh; base = (size_t)(b - 2048) * 2048; }
    const size_t i = base + (size_t)threadIdx.x * 8;
    float4 f0 = reinterpret_cast<const float4*>(src + i)[0];
    float4 f1 = reinterpret_cast<const float4*>(src + i)[1];
    U8 u;
    u.us[0] = f2h(f0.x); u.us[1] = f2h(f0.y); u.us[2] = f2h(f0.z); u.us[3] = f2h(f0.w);
    u.us[4] = f2h(f1.x); u.us[5] = f2h(f1.y); u.us[6] = f2h(f1.z); u.us[7] = f2h(f1.w);
    *reinterpret_cast<uint4*>(dst + i) = u.u4;
}

// ---------------------------------------------------------------------------
// Kernel 1: normalize memories, emit fragment-ordered F[h][tile64][chunk16][lane][8]
// chunks 0..7  (gs=g*2+s): QK A-frag (16x16x32), PERMUTED m:
//   elem = Mn[m_phys(g, lane&15)][d = s*32 + (lane>>4)*8 + j]
//   m_phys(g,r) = 32*(g>>1) + (r>>2)*8 + 4*(g&1) + (r&3)
// chunks 8..15 (c2=p*4+n): PV B-frag (16x16x32), physical m:
//   elem = Mn[32*p + (lane>>4)*8 + j][d = n*16 + (lane&15)]
// After QK+exp, lane's regs {g=2p,r0..3; g=2p+1,r0..3} are exactly the PV A-frag.
// [round-0 verbatim]
// ---------------------------------------------------------------------------
__global__ __launch_bounds__(256) void k_prep_mem(const float* __restrict__ mem,
                                                  unsigned short* __restrict__ F) {
    __shared__ float part[64][4];
    __shared__ float scale[64];
    __shared__ unsigned short Tn[64 * SW];

    const int h  = blockIdx.y;
    const int tl = blockIdx.x;
    const int m0 = tl * 64;
    const int tid = threadIdx.x;
    const int r = tid >> 2;
    const int c = tid & 3;

    const float* src = mem + ((size_t)(h * M_SZ + m0 + r)) * HD + c * 16;
    float v[16];
    float ss = 0.f;
#pragma unroll
    for (int i = 0; i < 4; i++) {
        float4 f = reinterpret_cast<const float4*>(src)[i];
        v[4*i+0] = f.x; v[4*i+1] = f.y; v[4*i+2] = f.z; v[4*i+3] = f.w;
        ss += f.x*f.x + f.y*f.y + f.z*f.z + f.w*f.w;
    }
    part[r][c] = ss;
    __syncthreads();
    if (tid < 64) {
        float s = part[tid][0] + part[tid][1] + part[tid][2] + part[tid][3];
        scale[tid] = rsqrtf(s);
    }
    __syncthreads();
    const float sc = scale[r];

    U8 a, b;
#pragma unroll
    for (int i = 0; i < 8; i++) { a.us[i] = f2h(v[i] * sc); b.us[i] = f2h(v[8 + i] * sc); }
    *reinterpret_cast<uint4*>(&Tn[r * SW + c * 16])     = a.u4;
    *reinterpret_cast<uint4*>(&Tn[r * SW + c * 16 + 8]) = b.u4;
    __syncthreads();

    const int w = tid >> 6, lane = tid & 63;
    const int l15 = lane & 15, quad = lane >> 4;
    unsigned short* Fd = F + ((size_t)(h * 64 + tl) * 16) * 512;

    // QK A-frag chunks (permuted m)
#pragma unroll
    for (int i = 0; i < 2; i++) {
        const int ch = w * 2 + i, g = ch >> 1, s = ch & 1;
        const int mp = 32 * (g >> 1) + ((l15 >> 2) * 8) + 4 * (g & 1) + (l15 & 3);
        uint4 vv = *reinterpret_cast<const uint4*>(&Tn[mp * SW + s * 32 + quad * 8]);
        *reinterpret_cast<uint4*>(Fd + ch * 512 + lane * 8) = vv;
    }
    // PV B-frag chunks (physical m)
#pragma unroll
    for (int i = 0; i < 2; i++) {
        const int c2 = w * 2 + i, p = c2 >> 2, n = c2 & 3;
        U8 u;
#pragma unroll
        for (int j = 0; j < 8; j++)
            u.us[j] = Tn[(32 * p + quad * 8 + j) * SW + n * 16 + l15];
        *reinterpret_cast<uint4*>(Fd + (8 + c2) * 512 + lane * 8) = u.u4;
    }
}

// ---------------------------------------------------------------------------
// Kernel 2 v2: q = xh @ Wh^T, m97-STRUCTURE staging. 128x64 tile (one head),
// BK=64, UNPADDED linear LDS [128][64]+[64][64] (24 KB), staged entirely via
// global_load_lds width=16 (6 wave-calls/k-step replace ~30 per-thread
// reg-staging ops — m151: 874 vs 646 TF). Frag reads eat m97's known bank
// conflicts. Fused L2 norm epilogue unchanged (SW-strided scratch reuses LDS).
// grid (32, 16) = 512 blocks -> 2 blocks/CU.
// ---------------------------------------------------------------------------
__global__ __launch_bounds__(256, 2) void k_qproj(const unsigned short* __restrict__ xh,
                                                  const unsigned short* __restrict__ Wh,
                                                  unsigned short* __restrict__ qn) {
    __shared__ __align__(16) unsigned short SM[12288];   // 24 KB
    unsigned short* As = SM;          // [128][64] f16, linear
    unsigned short* Bs = SM + 8192;   // [64][64]  f16, linear

    const int b0 = blockIdx.x * 128;
    const int n0 = blockIdx.y * 64;     // == h*64
    const int t = threadIdx.x;
    const int w = t >> 6, lane = t & 63;
    const int l15 = lane & 15, quad = lane >> 4;

    f32x4 acc[2][4] = {};

    for (int kb = 0; kb < K_IN; kb += 64) {
        __syncthreads();   // everyone done reading previous tile
        {
            // A: 16 KB = 16 wave-calls of 1 KB; 4 per wave.
            // LDS off = ca*1024B + lane*16B  <->  row = ca*8 + (lane>>3), col16 = (lane&7)*8
#pragma unroll
            for (int i = 0; i < 4; i++) {
                const int ca = w * 4 + i;
                const int row = ca * 8 + (lane >> 3);
                gload_lds16(xh + (size_t)(b0 + row) * K_IN + kb + (lane & 7) * 8,
                            As + ca * 512 + lane * 8);
            }
            // B: 8 KB = 8 wave-calls; 2 per wave.
#pragma unroll
            for (int i = 0; i < 2; i++) {
                const int cb = w * 2 + i;
                const int row = cb * 8 + (lane >> 3);
                gload_lds16(Wh + (size_t)(n0 + row) * K_IN + kb + (lane & 7) * 8,
                            Bs + cb * 512 + lane * 8);
            }
        }
        __syncthreads();   // vmcnt drained by barrier semantics; tile ready

#pragma unroll
        for (int s = 0; s < 2; s++) {
            f16x8 af[2];
#pragma unroll
            for (int qg = 0; qg < 2; qg++)
                af[qg] = ldsv8(&As[(w * 32 + qg * 16 + l15) * 64 + s * 32 + quad * 8]);
#pragma unroll
            for (int g = 0; g < 4; g++) {
                f16x8 bf_ = ldsv8(&Bs[(g * 16 + l15) * 64 + s * 32 + quad * 8]);
#pragma unroll
                for (int qg = 0; qg < 2; qg++)
                    acc[qg][g] = __builtin_amdgcn_mfma_f32_16x16x32_f16(af[qg], bf_, acc[qg][g], 0, 0, 0);
            }
        }
    }

    __syncthreads();
    unsigned short* Ct = SM;   // scratch 128 x SW (18.4 KB <= 24 KB)
#pragma unroll
    for (int qg = 0; qg < 2; qg++) {
        float ssq[4];
#pragma unroll
        for (int r = 0; r < 4; r++) {
            float s = 0.f;
#pragma unroll
            for (int g = 0; g < 4; g++) s += acc[qg][g][r] * acc[qg][g][r];
            ssq[r] = s;
        }
#pragma unroll
        for (int mask = 1; mask <= 8; mask <<= 1)
#pragma unroll
            for (int r = 0; r < 4; r++) ssq[r] += __shfl_xor(ssq[r], mask, 64);
#pragma unroll
        for (int r = 0; r < 4; r++) {
            float inv = rsqrtf(ssq[r]) * LOG2E;
#pragma unroll
            for (int g = 0; g < 4; g++)
                Ct[(w * 32 + qg * 16 + quad * 4 + r) * SW + g * 16 + l15] = f2h(acc[qg][g][r] * inv);
        }
    }
    __syncthreads();

    const int row = t >> 1, half = (t & 1) * 32;
    unsigned short* dq = qn + (size_t)(b0 + row) * 1024 + n0 + half;
#pragma unroll
    for (int i = 0; i < 4; i++)
        reinterpret_cast<uint4*>(dq)[i] = *reinterpret_cast<const uint4*>(&Ct[row * SW + half + i * 8]);
}

// ---------------------------------------------------------------------------
// Kernel 3: fused attention v7 — FROZEN at round-7 state (77.4 µs; at the
// family floor under the per-SIMD MFMA+VALU serialize model).
// ---------------------------------------------------------------------------
__global__ __launch_bounds__(256, 2) void k_attn(const unsigned short* __restrict__ qn,
                                                 const unsigned short* __restrict__ F,
                                                 float* __restrict__ out) {
    __shared__ unsigned short buf[4][8192];   // 4 x 16 KB

    const int b = blockIdx.x;
    const int h  = 2 * (b & 7) + (b >> 8);    // XCD k serves heads {2k, 2k+1}
    const int b0 = ((b >> 3) & 31) * 128;
    const int t = threadIdx.x;
    const int w = t >> 6, lane = t & 63;
    const int l15 = lane & 15, quad = lane >> 4;

    const f32x4 Z = {0.f, 0.f, 0.f, 0.f};

    // Q as B-operand of 16x16x32: lane holds Q[q=l15][d = s*32 + quad*8 + j]
    f16x8 qf[2][2];
#pragma unroll
    for (int qg = 0; qg < 2; qg++)
#pragma unroll
        for (int s = 0; s < 2; s++) {
            U8 u;
            u.u4 = *reinterpret_cast<const uint4*>(
                qn + (size_t)(b0 + w * 32 + qg * 16 + l15) * 1024 + h * 64 + s * 32 + quad * 8);
            qf[qg][s] = u.h8;
        }

    const unsigned short* Fh = F + (size_t)h * 64 * 8192;

    f32x4 accO[2][4] = {};
    float lsum[2] = {0.f, 0.f};

    // pipeline register state (double-buffered)
    f16x8 puA[2][2], puB[2][2];   // P A-frags [qg][p]
    f16x8 bwA[8],   bwB[8];       // V B-frags [p*4+n]

#if __has_builtin(__builtin_amdgcn_fdot2)
    const f16x2 one2 = {(_Float16)1.f, (_Float16)1.f};
#define LSUM4(qgi, puv)                                                          \
    {                                                                            \
        float s_ = lsum[qgi];                                                    \
        s_ = __builtin_amdgcn_fdot2(__builtin_bit_cast(f16x2, (puv).ui[0]), one2, s_, false); \
        s_ = __builtin_amdgcn_fdot2(__builtin_bit_cast(f16x2, (puv).ui[1]), one2, s_, false); \
        s_ = __builtin_amdgcn_fdot2(__builtin_bit_cast(f16x2, (puv).ui[2]), one2, s_, false); \
        s_ = __builtin_amdgcn_fdot2(__builtin_bit_cast(f16x2, (puv).ui[3]), one2, s_, false); \
        lsum[qgi] = s_;                                                          \
    }
#else
#define LSUM4(qgi, puv)                                                          \
    {                                                                            \
        float a0 = (float)(puv).h8[0] + (float)(puv).h8[1];                      \
        float a1 = (float)(puv).h8[2] + (float)(puv).h8[3];                      \
        float a2 = (float)(puv).h8[4] + (float)(puv).h8[5];                      \
        float a3 = (float)(puv).h8[6] + (float)(puv).h8[7];                      \
        lsum[qgi] += (a0 + a1) + (a2 + a3);                                      \
    }
#endif

    // ---- prologue: stage tiles 0..2, compute pu(0)/bw(0) into set A ----
#pragma unroll
    for (int tp = 0; tp < 3; tp++)
#pragma unroll
        for (int i = 0; i < 4; i++) {
            const int ch = w * 4 + i;
            gload_lds16(Fh + (size_t)tp * 8192 + ch * 512 + lane * 8, &buf[tp][ch * 512]);
        }
    __syncthreads();
    {
        f16x8 am[8];
#pragma unroll
        for (int ch = 0; ch < 8; ch++) am[ch] = ldsv8(&buf[0][ch * 512 + lane * 8]);
#pragma unroll
        for (int ch = 0; ch < 8; ch++) bwA[ch] = ldsv8(&buf[0][(8 + ch) * 512 + lane * 8]);
#pragma unroll
        for (int g = 0; g < 4; g++) {
            const int qg = g >> 1, p = g & 1;
            f32x4 t0 = __builtin_amdgcn_mfma_f32_16x16x32_f16(am[4*p+0], qf[qg][0], Z, 0, 0, 0);
            t0 = __builtin_amdgcn_mfma_f32_16x16x32_f16(am[4*p+1], qf[qg][1], t0, 0, 0, 0);
            f32x4 t1 = __builtin_amdgcn_mfma_f32_16x16x32_f16(am[4*p+2], qf[qg][0], Z, 0, 0, 0);
            t1 = __builtin_amdgcn_mfma_f32_16x16x32_f16(am[4*p+3], qf[qg][1], t1, 0, 0, 0);
            float p0 = EXP2F(t0[0]), p1 = EXP2F(t0[1]), p2 = EXP2F(t0[2]), p3 = EXP2F(t0[3]);
            float p4 = EXP2F(t1[0]), p5 = EXP2F(t1[1]), p6 = EXP2F(t1[2]), p7 = EXP2F(t1[3]);
            U8 pu;
#if __has_builtin(__builtin_amdgcn_cvt_pkrtz)
            pu.ui[0] = __builtin_bit_cast(unsigned int, __builtin_amdgcn_cvt_pkrtz(p0, p1));
            pu.ui[1] = __builtin_bit_cast(unsigned int, __builtin_amdgcn_cvt_pkrtz(p2, p3));
            pu.ui[2] = __builtin_bit_cast(unsigned int, __builtin_amdgcn_cvt_pkrtz(p4, p5));
            pu.ui[3] = __builtin_bit_cast(unsigned int, __builtin_amdgcn_cvt_pkrtz(p6, p7));
#else
            pu.us[0]=f2h(p0); pu.us[1]=f2h(p1); pu.us[2]=f2h(p2); pu.us[3]=f2h(p3);
            pu.us[4]=f2h(p4); pu.us[5]=f2h(p5); pu.us[6]=f2h(p6); pu.us[7]=f2h(p7);
#endif
            LSUM4(qg, pu);
            puA[qg][p] = pu.h8;
        }
    }

    // ---- pipelined body: PV(tl) || QK(tl+1); barrier hoisted to window ----
    auto body = [&](int tl, f16x8 (&puC)[2][2], f16x8 (&bwC)[8],
                            f16x8 (&puN)[2][2], f16x8 (&bwN)[8]) {
        const unsigned short* lb = buf[(tl + 1) & 3];
        f16x8 amn[8];
#pragma unroll
        for (int ch = 0; ch < 8; ch++) amn[ch] = ldsv8(&lb[ch * 512 + lane * 8]);
#pragma unroll
        for (int ch = 0; ch < 8; ch++) bwN[ch] = ldsv8(&lb[(8 + ch) * 512 + lane * 8]);
        if (tl + 3 < 64) {   // stage tile tl+3 into buf[(tl+3)&3]
            const unsigned short* gsrc = Fh + (size_t)(tl + 3) * 8192;
#pragma unroll
            for (int i = 0; i < 4; i++) {
                const int ch = w * 4 + i;
                gload_lds16(gsrc + ch * 512 + lane * 8, &buf[(tl + 3) & 3][ch * 512]);
            }
        }

        f32x4 sa[4], sb[4];
        auto expPack = [&](int g) {
            const int qg = g >> 1, p = g & 1;
            float p0 = EXP2F(sa[g][0]), p1 = EXP2F(sa[g][1]), p2 = EXP2F(sa[g][2]), p3 = EXP2F(sa[g][3]);
            float p4 = EXP2F(sb[g][0]), p5 = EXP2F(sb[g][1]), p6 = EXP2F(sb[g][2]), p7 = EXP2F(sb[g][3]);
            U8 pu;
#if __has_builtin(__builtin_amdgcn_cvt_pkrtz)
            pu.ui[0] = __builtin_bit_cast(unsigned int, __builtin_amdgcn_cvt_pkrtz(p0, p1));
            pu.ui[1] = __builtin_bit_cast(unsigned int, __builtin_amdgcn_cvt_pkrtz(p2, p3));
            pu.ui[2] = __builtin_bit_cast(unsigned int, __builtin_amdgcn_cvt_pkrtz(p4, p5));
            pu.ui[3] = __builtin_bit_cast(unsigned int, __builtin_amdgcn_cvt_pkrtz(p6, p7));
#else
            pu.us[0]=f2h(p0); pu.us[1]=f2h(p1); pu.us[2]=f2h(p2); pu.us[3]=f2h(p3);
            pu.us[4]=f2h(p4); pu.us[5]=f2h(p5); pu.us[6]=f2h(p6); pu.us[7]=f2h(p7);
#endif
            LSUM4(qg, pu);
            puN[qg][p] = pu.h8;
        };

#pragma unroll
        for (int g = 0; g < 4; g++) {
            const int qg = g >> 1, p = g & 1;
            __builtin_amdgcn_s_setprio(1);
            // QK group g of tile tl+1
            f32x4 t0 = __builtin_amdgcn_mfma_f32_16x16x32_f16(amn[4*p+0], qf[qg][0], Z, 0, 0, 0);
            t0 = __builtin_amdgcn_mfma_f32_16x16x32_f16(amn[4*p+1], qf[qg][1], t0, 0, 0, 0);
            f32x4 t1 = __builtin_amdgcn_mfma_f32_16x16x32_f16(amn[4*p+2], qf[qg][0], Z, 0, 0, 0);
            t1 = __builtin_amdgcn_mfma_f32_16x16x32_f16(amn[4*p+3], qf[qg][1], t1, 0, 0, 0);
            sa[g] = t0; sb[g] = t1;
            // PV group g of tile tl (independent of the QK above)
#pragma unroll
            for (int n = 0; n < 4; n++)
                accO[qg][n] = __builtin_amdgcn_mfma_f32_16x16x32_f16(puC[qg][p], bwC[p * 4 + n], accO[qg][n], 0, 0, 0);
            __builtin_amdgcn_s_setprio(0);
            // exp of the PREVIOUS group (its QK results are long since ready)
            if (g >= 1) expPack(g - 1);
        }
        expPack(3);
    };

    // windows of 2 tiles: barrier at even tl (0,2,...,62) -> 32 in-loop syncs
    for (int tt = 0; tt < 31; ++tt) {
        __syncthreads();
        body(2 * tt,     puA, bwA, puB, bwB);
        body(2 * tt + 1, puB, bwB, puA, bwA);
    }
    __syncthreads();
    body(62, puA, bwA, puB, bwB);

    // ---- epilogue: PV(63) from register set B, then normalize + store ----
#pragma unroll
    for (int g = 0; g < 4; g++) {
        const int qg = g >> 1, p = g & 1;
#pragma unroll
        for (int n = 0; n < 4; n++)
            accO[qg][n] = __builtin_amdgcn_mfma_f32_16x16x32_f16(puB[qg][p], bwB[p * 4 + n], accO[qg][n], 0, 0, 0);
    }

#pragma unroll
    for (int qg = 0; qg < 2; qg++) {
        float s = lsum[qg];
        s += __shfl_xor(s, 16, 64);
        s += __shfl_xor(s, 32, 64);
        float inv = 8.0f / s;    // sqrt(HEAD_DIM) = 8
#pragma unroll
        for (int r = 0; r < 4; r++) {
            float iv = __shfl(inv, quad * 4 + r, 64);
            float* po = out + (size_t)(b0 + w * 32 + qg * 16 + quad * 4 + r) * 1024 + h * 64;
#pragma unroll
            for (int n = 0; n < 4; n++)
                po[n * 16 + l15] = accO[qg][n][r] * iv;
        }
    }
}

// ---------------------------------------------------------------------------
extern "C" void kernel_launch(void* const* d_in, const int* in_sizes, int n_in,
                              void* d_out, int out_size, void* d_ws, size_t ws_size,
                              hipStream_t stream) {
    (void)in_sizes; (void)n_in; (void)out_size; (void)ws_size;
    const float* x   = (const float*)d_in[0];
    const float* Wq  = (const float*)d_in[1];
    const float* mem = (const float*)d_in[2];
    float* out = (float*)d_out;

    unsigned short* qn = (unsigned short*)d_ws;                 // 8 MB
    unsigned short* F  = qn + (size_t)B_SZ * 1024;              // 16 MB (frag-ordered)
    unsigned short* xh = F  + (size_t)HEADS * 64 * 16 * 512;    // 8 MB
    unsigned short* Wh = xh + (size_t)B_SZ * K_IN;              // 2 MB   (total 34 MB)

    k_conv    <<<2560, 256, 0, stream>>>(x, Wq, xh, Wh);
    k_prep_mem<<<dim3(64, 16), 256, 0, stream>>>(mem, F);
    k_qproj   <<<dim3(32, 16), 256, 0, stream>>>(xh, Wh, qn);
    k_attn    <<<512, 256, 0, stream>>>(qn, F, out);
}